// Round 9
// baseline (1292.854 us; speedup 1.0000x reference)
//
#include <hip/hip_runtime.h>
#include <hip/hip_bf16.h>
#include <stdint.h>

#define DIM 1024
#define NTOK 16384
#define SEQ 4096
#define BLKLEN 128
#define NHEAD 16
#define DH 64

typedef short bf16x8 __attribute__((ext_vector_type(8)));
typedef float f32x4 __attribute__((ext_vector_type(4)));

static __device__ __forceinline__ unsigned short f2bf(float f) {
  union { float f; uint32_t u; } v; v.f = f;
  return (unsigned short)((v.u + 0x7FFFu + ((v.u >> 16) & 1u)) >> 16);
}
static __device__ __forceinline__ float bf2f(unsigned short h) {
  union { uint32_t u; float f; } v; v.u = ((uint32_t)h) << 16;
  return v.f;
}
static __device__ __forceinline__ uint32_t pk2(float a, float b) {
  __hip_bfloat162 h = __float22bfloat162_rn(make_float2(a, b));
  union { __hip_bfloat162 h; uint32_t u; } c; c.h = h; return c.u;
}
// one packed-bf16 dword -> two floats (lo elem = low 16 bits)
static __device__ __forceinline__ void up2(uint32_t w, float& a, float& b) {
  union { uint32_t u; float f; } x, y;
  x.u = w << 16; y.u = w & 0xFFFF0000u;
  a = x.f; b = y.f;
}
// 8 fp32 -> packed bf16 (RNE), hi only (one-sided split: W carries the lo part)
static __device__ __forceinline__ uint4 cvt4(float4 x, float4 y) {
  return make_uint4(pk2(x.x, x.y), pk2(x.z, x.w), pk2(y.x, y.y), pk2(y.z, y.w));
}

// ---------- W [k][m] -> Wt [m][k], bf16 hi/lo split, 3 weights ----------
__global__ void wsplit_kernel(const float* __restrict__ w1, const float* __restrict__ w2,
                              const float* __restrict__ w3,
                              unsigned short* __restrict__ hi, unsigned short* __restrict__ lo) {
  const float* w = (blockIdx.z == 0) ? w1 : (blockIdx.z == 1) ? w2 : w3;
  unsigned short* hp = hi + (size_t)blockIdx.z * DIM * DIM;
  unsigned short* lp = lo + (size_t)blockIdx.z * DIM * DIM;
  __shared__ float t[64][65];
  int m0 = blockIdx.x * 64, k0 = blockIdx.y * 64;
  int tx = threadIdx.x, ty = threadIdx.y;
  for (int i = ty; i < 64; i += 4)
    t[i][tx] = w[(size_t)(k0 + i) * DIM + m0 + tx];
  __syncthreads();
  for (int i = ty; i < 64; i += 4) {
    float x = t[tx][i];
    unsigned short h = f2bf(x);
    size_t o = (size_t)(m0 + i) * DIM + k0 + tx;
    hp[o] = h;
    lp[o] = f2bf(x - bf2f(h));
  }
}

// ---------- QKV GEMM: [16384,1024] x [1024,1024]x3, one-sided-split 2-pass MFMA ----
// A = bf16(X) (single rounding, in-register cvt). B = Whi + Wlo (exact split).
#define BK 32
#define AST 40  // padded LDS row stride (bf16 elems)

__global__ __launch_bounds__(256, 4) void qkv_gemm_kernel(
    const float* __restrict__ X,
    const unsigned short* __restrict__ Whi, const unsigned short* __restrict__ Wlo,
    const float* __restrict__ b1, const float* __restrict__ b2, const float* __restrict__ b3,
    float* __restrict__ Qp, float* __restrict__ Kp, float* __restrict__ Vp) {
  __shared__ unsigned short Ah[128 * AST], Bh[128 * AST], Bl[128 * AST];  // 30720 B

  int tile_n = blockIdx.x;  // 0..23 (3 weights x 8 col tiles)
  int tile_m = blockIdx.y;  // 0..127
  int wsel = tile_n >> 3;
  int colw0 = (tile_n & 7) * 128;
  const unsigned short* wh = Whi + (size_t)wsel * DIM * DIM;
  const unsigned short* wl = Wlo + (size_t)wsel * DIM * DIM;
  const float* bias = (wsel == 0) ? b1 : (wsel == 1) ? b2 : b3;
  float* o = (wsel == 0) ? Qp : (wsel == 1) ? Kp : Vp;

  int t = threadIdx.x;
  int wid = t >> 6, lane = t & 63;
  int wr = wid >> 1, wc = wid & 1;

  f32x4 acc[4][4];
#pragma unroll
  for (int i = 0; i < 4; ++i)
#pragma unroll
    for (int j = 0; j < 4; ++j) acc[i][j] = (f32x4){0.f, 0.f, 0.f, 0.f};

  int srow = t >> 2;     // 0..63
  int kc = (t & 3) * 8;  // 0,8,16,24 (elems along K)
  const size_t arow = (size_t)tile_m * 128;

  const float* pa0 = X + (arow + srow) * DIM + kc;
  const float* pa1 = X + (arow + srow + 64) * DIM + kc;
  const unsigned short* pb0 = wh + (size_t)(colw0 + srow) * DIM + kc;
  const unsigned short* pb1 = wh + (size_t)(colw0 + srow + 64) * DIM + kc;
  const unsigned short* plb0 = wl + (size_t)(colw0 + srow) * DIM + kc;
  const unsigned short* plb1 = wl + (size_t)(colw0 + srow + 64) * DIM + kc;

  uint32_t lw0 = srow * AST + kc;
  uint32_t lw1 = (srow + 64) * AST + kc;

  int frow = lane & 15;
  int fk = (lane >> 4) * 8;

  float4 ra00 = *(const float4*)(pa0), ra01 = *(const float4*)(pa0 + 4);
  float4 ra10 = *(const float4*)(pa1), ra11 = *(const float4*)(pa1 + 4);
  uint4 rbh0 = *(const uint4*)(pb0), rbh1 = *(const uint4*)(pb1);
  uint4 rbl0 = *(const uint4*)(plb0), rbl1 = *(const uint4*)(plb1);

  for (int k0 = 0; k0 < DIM; k0 += BK) {
    uint4 ah0 = cvt4(ra00, ra01);
    uint4 ah1 = cvt4(ra10, ra11);
    __syncthreads();
    *(uint4*)&Ah[lw0] = ah0; *(uint4*)&Ah[lw1] = ah1;
    *(uint4*)&Bh[lw0] = rbh0; *(uint4*)&Bh[lw1] = rbh1;
    *(uint4*)&Bl[lw0] = rbl0; *(uint4*)&Bl[lw1] = rbl1;
    __syncthreads();
    if (k0 + BK < DIM) {  // prefetch next K-tile into regs
      int off = k0 + BK;
      ra00 = *(const float4*)(pa0 + off); ra01 = *(const float4*)(pa0 + off + 4);
      ra10 = *(const float4*)(pa1 + off); ra11 = *(const float4*)(pa1 + off + 4);
      rbh0 = *(const uint4*)(pb0 + off); rbh1 = *(const uint4*)(pb1 + off);
      rbl0 = *(const uint4*)(plb0 + off); rbl1 = *(const uint4*)(plb1 + off);
    }
    bf16x8 fa[4], fbh[4], fbl[4];
#pragma unroll
    for (int m = 0; m < 4; ++m) {
      int r = wr * 64 + m * 16 + frow;
      fa[m] = *(const bf16x8*)&Ah[r * AST + fk];
    }
#pragma unroll
    for (int n = 0; n < 4; ++n) {
      int c = wc * 64 + n * 16 + frow;
      fbh[n] = *(const bf16x8*)&Bh[c * AST + fk];
      fbl[n] = *(const bf16x8*)&Bl[c * AST + fk];
    }
#pragma unroll
    for (int m = 0; m < 4; ++m)
#pragma unroll
      for (int n = 0; n < 4; ++n) {
        acc[m][n] = __builtin_amdgcn_mfma_f32_16x16x32_bf16(fa[m], fbh[n], acc[m][n], 0, 0, 0);
        acc[m][n] = __builtin_amdgcn_mfma_f32_16x16x32_bf16(fa[m], fbl[n], acc[m][n], 0, 0, 0);
      }
  }

  int fgrp = lane >> 4;
#pragma unroll
  for (int n = 0; n < 4; ++n) {
    int col = colw0 + wc * 64 + n * 16 + frow;
    float bv = bias[col];
#pragma unroll
    for (int m = 0; m < 4; ++m) {
      size_t row = arow + wr * 64 + m * 16 + fgrp * 4;
#pragma unroll
      for (int r = 0; r < 4; ++r)
        o[(row + r) * DIM + col] = acc[m][n][r] + bv;
    }
  }
}

// ---------- block-local attention, one block per (h,b,n) ----------
// bf16 LDS tiles for Q/K/P (f32 math in regs): LDS 69,632 B -> 2 blocks/CU.
// Vg aliases out; each block stages its own V region to LDS before writing it.
#define PST 136  // bf16 row stride: 272 B keeps 16-B alignment per row

__global__ __launch_bounds__(256, 2) void attn_kernel(
    const float* __restrict__ Qg, const float* __restrict__ Kg, const float* Vg,
    const int* __restrict__ mask, const float* __restrict__ inputs, float* out) {
  __shared__ __align__(16) unsigned char smem[69632];
  unsigned short* Qt = (unsigned short*)smem;   // [64][PST] bf16, d-major (transposed)
  unsigned short* Kt = Qt + 64 * PST;           // [64][PST] bf16
  unsigned short* Pt = (unsigned short*)smem;   // [128][PST] bf16, reuses Qt+Kt exactly
  float* Vs = (float*)(smem + 2 * 64 * PST * 2);  // [128][68] f32 (offset 34816)

  int blk = blockIdx.x;
  int n = blk & 31;
  int b = (blk >> 5) & 3;
  int h = blk >> 7;
  size_t tok0 = (size_t)b * SEQ + (size_t)n * BLKLEN;
  int col0 = h * DH;

  int t = threadIdx.x;
  {
    int r = t >> 1;
    int d0 = (t & 1) * 32;
    const float* qp = Qg + (tok0 + r) * DIM + col0 + d0;
    const float* kp = Kg + (tok0 + r) * DIM + col0 + d0;
    const float* vp = Vg + (tok0 + r) * DIM + col0 + d0;
#pragma unroll
    for (int i = 0; i < 8; ++i) {
      float4 q4 = *(const float4*)(qp + i * 4);
      float4 k4 = *(const float4*)(kp + i * 4);
      float4 v4 = *(const float4*)(vp + i * 4);
      int d = d0 + i * 4;
      Qt[(d + 0) * PST + r] = f2bf(q4.x); Qt[(d + 1) * PST + r] = f2bf(q4.y);
      Qt[(d + 2) * PST + r] = f2bf(q4.z); Qt[(d + 3) * PST + r] = f2bf(q4.w);
      Kt[(d + 0) * PST + r] = f2bf(k4.x); Kt[(d + 1) * PST + r] = f2bf(k4.y);
      Kt[(d + 2) * PST + r] = f2bf(k4.z); Kt[(d + 3) * PST + r] = f2bf(k4.w);
      *(float4*)&Vs[r * 68 + d] = v4;
    }
  }
  __syncthreads();

  int qt = t >> 4, kt = t & 15;
  int q0 = qt * 8, k0 = kt * 8;
  float s[8][8];
#pragma unroll
  for (int i = 0; i < 8; ++i)
#pragma unroll
    for (int j = 0; j < 8; ++j) s[i][j] = 0.f;

#pragma unroll 4
  for (int d = 0; d < 64; ++d) {
    uint4 qw = *(const uint4*)&Qt[d * PST + q0];
    uint4 kw = *(const uint4*)&Kt[d * PST + k0];
    float qv[8], kv[8];
    up2(qw.x, qv[0], qv[1]); up2(qw.y, qv[2], qv[3]);
    up2(qw.z, qv[4], qv[5]); up2(qw.w, qv[6], qv[7]);
    up2(kw.x, kv[0], kv[1]); up2(kw.y, kv[2], kv[3]);
    up2(kw.z, kv[4], kv[5]); up2(kw.w, kv[6], kv[7]);
#pragma unroll
    for (int i = 0; i < 8; ++i)
#pragma unroll
      for (int j = 0; j < 8; ++j) s[i][j] += qv[i] * kv[j];
  }

  // mask penalty depends only on query row; reproduces reference fp32 swamping
  float pen[8];
#pragma unroll
  for (int i = 0; i < 8; ++i)
    pen[i] = (1.0f - (float)mask[(tok0 + q0 + i) * DIM + col0]) * -1e10f;

  float mx[8], sm[8], inv[8];
#pragma unroll
  for (int i = 0; i < 8; ++i) {
    float m0 = -3.4e38f;
#pragma unroll
    for (int j = 0; j < 8; ++j) {
      s[i][j] = s[i][j] * 0.125f + pen[i];
      m0 = fmaxf(m0, s[i][j]);
    }
    mx[i] = m0;
  }
#pragma unroll
  for (int x = 1; x < 16; x <<= 1)
#pragma unroll
    for (int i = 0; i < 8; ++i) mx[i] = fmaxf(mx[i], __shfl_xor(mx[i], x));
#pragma unroll
  for (int i = 0; i < 8; ++i) {
    float a = 0.f;
#pragma unroll
    for (int j = 0; j < 8; ++j) {
      s[i][j] = __expf(s[i][j] - mx[i]);
      a += s[i][j];
    }
    sm[i] = a;
  }
#pragma unroll
  for (int x = 1; x < 16; x <<= 1)
#pragma unroll
    for (int i = 0; i < 8; ++i) sm[i] += __shfl_xor(sm[i], x);
#pragma unroll
  for (int i = 0; i < 8; ++i) inv[i] = 1.0f / sm[i];

  __syncthreads();  // done reading Qt/Kt; safe to overwrite with Pt
#pragma unroll
  for (int j = 0; j < 8; ++j)
#pragma unroll
    for (int i = 0; i < 8; i += 2) {
      uint32_t pw = pk2(s[i][j] * inv[i], s[i + 1][j] * inv[i + 1]);
      *(uint32_t*)&Pt[(k0 + j) * PST + q0 + i] = pw;  // elem idx even -> 4B aligned
    }
  __syncthreads();

  int dt = t & 15;
  int q0b = (t >> 4) * 8;
  int dv0 = dt * 4;
  float o0[8], o1[8], o2[8], o3[8];
#pragma unroll
  for (int i = 0; i < 8; ++i) { o0[i] = 0.f; o1[i] = 0.f; o2[i] = 0.f; o3[i] = 0.f; }

#pragma unroll 4
  for (int k = 0; k < 128; ++k) {
    uint4 pw = *(const uint4*)&Pt[k * PST + q0b];
    float pv[8];
    up2(pw.x, pv[0], pv[1]); up2(pw.y, pv[2], pv[3]);
    up2(pw.z, pv[4], pv[5]); up2(pw.w, pv[6], pv[7]);
    float4 vv = *(const float4*)&Vs[k * 68 + dv0];
#pragma unroll
    for (int i = 0; i < 8; ++i) {
      o0[i] += pv[i] * vv.x;
      o1[i] += pv[i] * vv.y;
      o2[i] += pv[i] * vv.z;
      o3[i] += pv[i] * vv.w;
    }
  }
#pragma unroll
  for (int i = 0; i < 8; ++i) {
    size_t idx = (tok0 + q0b + i) * DIM + col0 + dv0;
    float4 inp = *(const float4*)(inputs + idx);
    float4 r;
    r.x = o0[i] + inp.x; r.y = o1[i] + inp.y; r.z = o2[i] + inp.z; r.w = o3[i] + inp.w;
    *(float4*)(out + idx) = r;
  }
}

// ---------- residual already applied; in-place LayerNorm over DIM ----------
__global__ __launch_bounds__(256) void ln_kernel(float* __restrict__ io,
                                                 const float* __restrict__ gamma,
                                                 const float* __restrict__ beta) {
  int row = blockIdx.x;
  int t = threadIdx.x;
  float4 x = *(const float4*)(io + (size_t)row * DIM + t * 4);
  float s = x.x + x.y + x.z + x.w;
  float q = x.x * x.x + x.y * x.y + x.z * x.z + x.w * x.w;
#pragma unroll
  for (int off = 1; off < 64; off <<= 1) {
    s += __shfl_xor(s, off);
    q += __shfl_xor(q, off);
  }
  __shared__ float red[8];
  int wid = t >> 6, lane = t & 63;
  if (lane == 0) { red[wid] = s; red[wid + 4] = q; }
  __syncthreads();
  s = red[0] + red[1] + red[2] + red[3];
  q = red[4] + red[5] + red[6] + red[7];
  float mu = s * (1.0f / 1024.0f);
  float var = q * (1.0f / 1024.0f) - mu * mu;
  float rs = 1.0f / sqrtf(var + 1e-3f);
  float4 g = *(const float4*)(gamma + t * 4);
  float4 be = *(const float4*)(beta + t * 4);
  float4 r;
  r.x = g.x * (x.x - mu) * rs + be.x;
  r.y = g.y * (x.y - mu) * rs + be.y;
  r.z = g.z * (x.z - mu) * rs + be.z;
  r.w = g.w * (x.w - mu) * rs + be.w;
  *(float4*)(io + (size_t)row * DIM + t * 4) = r;
}

extern "C" void kernel_launch(void* const* d_in, const int* in_sizes, int n_in,
                              void* d_out, int out_size, void* d_ws, size_t ws_size,
                              hipStream_t stream) {
  (void)in_sizes; (void)n_in; (void)out_size; (void)ws_size;
  const float* inputs = (const float*)d_in[0];
  const int* mask = (const int*)d_in[1];
  const float* w1 = (const float*)d_in[2];
  const float* b1 = (const float*)d_in[3];
  const float* w2 = (const float*)d_in[4];
  const float* b2 = (const float*)d_in[5];
  const float* w3 = (const float*)d_in[6];
  const float* b3 = (const float*)d_in[7];
  const float* gamma = (const float*)d_in[8];
  const float* beta = (const float*)d_in[9];
  float* out = (float*)d_out;

  // workspace layout (140 MB total):
  //   Whi @ 0       (6 MB)   Wlo @ 6 MB   (6 MB)
  //   Q   @ 12 MB   (64 MB)  K   @ 76 MB  (64 MB)
  //   V lives in d_out (GEMM writes it; attn reads it before overwriting — safe per-block)
  char* ws = (char*)d_ws;
  unsigned short* Whi = (unsigned short*)(ws);
  unsigned short* Wlo = (unsigned short*)(ws + ((size_t)6 << 20));
  float* Q = (float*)(ws + ((size_t)12 << 20));
  float* K = (float*)(ws + ((size_t)76 << 20));
  float* V = out;

  hipLaunchKernelGGL(wsplit_kernel, dim3(16, 16, 3), dim3(64, 4), 0, stream,
                     w1, w2, w3, Whi, Wlo);
  hipLaunchKernelGGL(qkv_gemm_kernel, dim3(24, 128), dim3(256), 0, stream,
                     inputs, Whi, Wlo, b1, b2, b3, Q, K, V);
  hipLaunchKernelGGL(attn_kernel, dim3(2048), dim3(256), 0, stream,
                     Q, K, V, mask, inputs, out);
  hipLaunchKernelGGL(ln_kernel, dim3(NTOK), dim3(256), 0, stream,
                     out, gamma, beta);
}

// Round 11
// 567.145 us; speedup vs baseline: 2.2796x; 2.2796x over previous
//
#include <hip/hip_runtime.h>
#include <hip/hip_bf16.h>
#include <stdint.h>

#define DIM 1024
#define NTOK 16384
#define SEQ 4096
#define BLKLEN 128
#define NHEAD 16
#define DH 64

typedef short bf16x8 __attribute__((ext_vector_type(8)));
typedef float f32x4 __attribute__((ext_vector_type(4)));

static __device__ __forceinline__ unsigned short f2bf(float f) {
  union { float f; uint32_t u; } v; v.f = f;
  return (unsigned short)((v.u + 0x7FFFu + ((v.u >> 16) & 1u)) >> 16);
}
static __device__ __forceinline__ float bf2f(unsigned short h) {
  union { uint32_t u; float f; } v; v.u = ((uint32_t)h) << 16;
  return v.f;
}
static __device__ __forceinline__ uint32_t pk2(float a, float b) {
  __hip_bfloat162 h = __float22bfloat162_rn(make_float2(a, b));
  union { __hip_bfloat162 h; uint32_t u; } c; c.h = h; return c.u;
}
// one packed-bf16 dword -> two floats (lo elem = low 16 bits)
static __device__ __forceinline__ void up2(uint32_t w, float& a, float& b) {
  union { uint32_t u; float f; } x, y;
  x.u = w << 16; y.u = w & 0xFFFF0000u;
  a = x.f; b = y.f;
}
// 8 fp32 -> packed bf16 (RNE), hi only (one-sided split: W carries the lo part)
static __device__ __forceinline__ uint4 cvt4(float4 x, float4 y) {
  return make_uint4(pk2(x.x, x.y), pk2(x.z, x.w), pk2(y.x, y.y), pk2(y.z, y.w));
}

// ---------- W [k][m] -> Wt [m][k], bf16 hi/lo split, 3 weights ----------
__global__ void wsplit_kernel(const float* __restrict__ w1, const float* __restrict__ w2,
                              const float* __restrict__ w3,
                              unsigned short* __restrict__ hi, unsigned short* __restrict__ lo) {
  const float* w = (blockIdx.z == 0) ? w1 : (blockIdx.z == 1) ? w2 : w3;
  unsigned short* hp = hi + (size_t)blockIdx.z * DIM * DIM;
  unsigned short* lp = lo + (size_t)blockIdx.z * DIM * DIM;
  __shared__ float t[64][65];
  int m0 = blockIdx.x * 64, k0 = blockIdx.y * 64;
  int tx = threadIdx.x, ty = threadIdx.y;
  for (int i = ty; i < 64; i += 4)
    t[i][tx] = w[(size_t)(k0 + i) * DIM + m0 + tx];
  __syncthreads();
  for (int i = ty; i < 64; i += 4) {
    float x = t[tx][i];
    unsigned short h = f2bf(x);
    size_t o = (size_t)(m0 + i) * DIM + k0 + tx;
    hp[o] = h;
    lp[o] = f2bf(x - bf2f(h));
  }
}

// ---------- QKV GEMM: [16384,1024] x [1024,1024]x3, one-sided-split 2-pass MFMA ----
// A = bf16(X) (single rounding, in-register cvt). B = Whi + Wlo (exact split).
// launch_bounds (256,2): R9 showed (256,4) caps unified VGPR+AGPR at 128 ->
// acc(64 AGPR) leaves 64 VGPR -> per-iter scratch spill (WRITE_SIZE 2.5GB,
// MfmaUtil 8.8%). Keep the allocator unconstrained at 2 waves/EU.
#define BK 32
#define AST 40  // padded LDS row stride (bf16 elems)

__global__ __launch_bounds__(256, 2) void qkv_gemm_kernel(
    const float* __restrict__ X,
    const unsigned short* __restrict__ Whi, const unsigned short* __restrict__ Wlo,
    const float* __restrict__ b1, const float* __restrict__ b2, const float* __restrict__ b3,
    float* __restrict__ Qp, float* __restrict__ Kp, float* __restrict__ Vp) {
  __shared__ unsigned short Ah[128 * AST], Bh[128 * AST], Bl[128 * AST];  // 30720 B

  int tile_n = blockIdx.x;  // 0..23 (3 weights x 8 col tiles)
  int tile_m = blockIdx.y;  // 0..127
  int wsel = tile_n >> 3;
  int colw0 = (tile_n & 7) * 128;
  const unsigned short* wh = Whi + (size_t)wsel * DIM * DIM;
  const unsigned short* wl = Wlo + (size_t)wsel * DIM * DIM;
  const float* bias = (wsel == 0) ? b1 : (wsel == 1) ? b2 : b3;
  float* o = (wsel == 0) ? Qp : (wsel == 1) ? Kp : Vp;

  int t = threadIdx.x;
  int wid = t >> 6, lane = t & 63;
  int wr = wid >> 1, wc = wid & 1;

  f32x4 acc[4][4];
#pragma unroll
  for (int i = 0; i < 4; ++i)
#pragma unroll
    for (int j = 0; j < 4; ++j) acc[i][j] = (f32x4){0.f, 0.f, 0.f, 0.f};

  int srow = t >> 2;     // 0..63
  int kc = (t & 3) * 8;  // 0,8,16,24 (elems along K)
  const size_t arow = (size_t)tile_m * 128;

  const float* pa0 = X + (arow + srow) * DIM + kc;
  const float* pa1 = X + (arow + srow + 64) * DIM + kc;
  const unsigned short* pb0 = wh + (size_t)(colw0 + srow) * DIM + kc;
  const unsigned short* pb1 = wh + (size_t)(colw0 + srow + 64) * DIM + kc;
  const unsigned short* plb0 = wl + (size_t)(colw0 + srow) * DIM + kc;
  const unsigned short* plb1 = wl + (size_t)(colw0 + srow + 64) * DIM + kc;

  uint32_t lw0 = srow * AST + kc;
  uint32_t lw1 = (srow + 64) * AST + kc;

  int frow = lane & 15;
  int fk = (lane >> 4) * 8;

  float4 ra00 = *(const float4*)(pa0), ra01 = *(const float4*)(pa0 + 4);
  float4 ra10 = *(const float4*)(pa1), ra11 = *(const float4*)(pa1 + 4);
  uint4 rbh0 = *(const uint4*)(pb0), rbh1 = *(const uint4*)(pb1);
  uint4 rbl0 = *(const uint4*)(plb0), rbl1 = *(const uint4*)(plb1);

  for (int k0 = 0; k0 < DIM; k0 += BK) {
    uint4 ah0 = cvt4(ra00, ra01);
    uint4 ah1 = cvt4(ra10, ra11);
    __syncthreads();
    *(uint4*)&Ah[lw0] = ah0; *(uint4*)&Ah[lw1] = ah1;
    *(uint4*)&Bh[lw0] = rbh0; *(uint4*)&Bh[lw1] = rbh1;
    *(uint4*)&Bl[lw0] = rbl0; *(uint4*)&Bl[lw1] = rbl1;
    __syncthreads();
    if (k0 + BK < DIM) {  // prefetch next K-tile into regs
      int off = k0 + BK;
      ra00 = *(const float4*)(pa0 + off); ra01 = *(const float4*)(pa0 + off + 4);
      ra10 = *(const float4*)(pa1 + off); ra11 = *(const float4*)(pa1 + off + 4);
      rbh0 = *(const uint4*)(pb0 + off); rbh1 = *(const uint4*)(pb1 + off);
      rbl0 = *(const uint4*)(plb0 + off); rbl1 = *(const uint4*)(plb1 + off);
    }
    bf16x8 fa[4], fbh[4], fbl[4];
#pragma unroll
    for (int m = 0; m < 4; ++m) {
      int r = wr * 64 + m * 16 + frow;
      fa[m] = *(const bf16x8*)&Ah[r * AST + fk];
    }
#pragma unroll
    for (int n = 0; n < 4; ++n) {
      int c = wc * 64 + n * 16 + frow;
      fbh[n] = *(const bf16x8*)&Bh[c * AST + fk];
      fbl[n] = *(const bf16x8*)&Bl[c * AST + fk];
    }
#pragma unroll
    for (int m = 0; m < 4; ++m)
#pragma unroll
      for (int n = 0; n < 4; ++n) {
        acc[m][n] = __builtin_amdgcn_mfma_f32_16x16x32_bf16(fa[m], fbh[n], acc[m][n], 0, 0, 0);
        acc[m][n] = __builtin_amdgcn_mfma_f32_16x16x32_bf16(fa[m], fbl[n], acc[m][n], 0, 0, 0);
      }
  }

  int fgrp = lane >> 4;
#pragma unroll
  for (int n = 0; n < 4; ++n) {
    int col = colw0 + wc * 64 + n * 16 + frow;
    float bv = bias[col];
#pragma unroll
    for (int m = 0; m < 4; ++m) {
      size_t row = arow + wr * 64 + m * 16 + fgrp * 4;
#pragma unroll
      for (int r = 0; r < 4; ++r)
        o[(row + r) * DIM + col] = acc[m][n][r] + bv;
    }
  }
}

// ---------- block-local attention, one block per (h,b,n) ----------
// bf16 LDS tiles for Q/K/P (f32 math in regs): LDS 69,632 B -> 2 blocks/CU.
// Vg aliases out; each block stages its own V region to LDS before writing it.
#define PST 136  // bf16 row stride: 272 B keeps 16-B alignment per row

__global__ __launch_bounds__(256, 2) void attn_kernel(
    const float* __restrict__ Qg, const float* __restrict__ Kg, const float* Vg,
    const int* __restrict__ mask, const float* __restrict__ inputs, float* out) {
  __shared__ __align__(16) unsigned char smem[69632];
  unsigned short* Qt = (unsigned short*)smem;   // [64][PST] bf16, d-major (transposed)
  unsigned short* Kt = Qt + 64 * PST;           // [64][PST] bf16
  unsigned short* Pt = (unsigned short*)smem;   // [128][PST] bf16, reuses Qt+Kt exactly
  float* Vs = (float*)(smem + 2 * 64 * PST * 2);  // [128][68] f32 (offset 34816)

  int blk = blockIdx.x;
  int n = blk & 31;
  int b = (blk >> 5) & 3;
  int h = blk >> 7;
  size_t tok0 = (size_t)b * SEQ + (size_t)n * BLKLEN;
  int col0 = h * DH;

  int t = threadIdx.x;
  {
    int r = t >> 1;
    int d0 = (t & 1) * 32;
    const float* qp = Qg + (tok0 + r) * DIM + col0 + d0;
    const float* kp = Kg + (tok0 + r) * DIM + col0 + d0;
    const float* vp = Vg + (tok0 + r) * DIM + col0 + d0;
#pragma unroll
    for (int i = 0; i < 8; ++i) {
      float4 q4 = *(const float4*)(qp + i * 4);
      float4 k4 = *(const float4*)(kp + i * 4);
      float4 v4 = *(const float4*)(vp + i * 4);
      int d = d0 + i * 4;
      Qt[(d + 0) * PST + r] = f2bf(q4.x); Qt[(d + 1) * PST + r] = f2bf(q4.y);
      Qt[(d + 2) * PST + r] = f2bf(q4.z); Qt[(d + 3) * PST + r] = f2bf(q4.w);
      Kt[(d + 0) * PST + r] = f2bf(k4.x); Kt[(d + 1) * PST + r] = f2bf(k4.y);
      Kt[(d + 2) * PST + r] = f2bf(k4.z); Kt[(d + 3) * PST + r] = f2bf(k4.w);
      *(float4*)&Vs[r * 68 + d] = v4;
    }
  }
  __syncthreads();

  int qt = t >> 4, kt = t & 15;
  int q0 = qt * 8, k0 = kt * 8;
  float s[8][8];
#pragma unroll
  for (int i = 0; i < 8; ++i)
#pragma unroll
    for (int j = 0; j < 8; ++j) s[i][j] = 0.f;

#pragma unroll 4
  for (int d = 0; d < 64; ++d) {
    uint4 qw = *(const uint4*)&Qt[d * PST + q0];
    uint4 kw = *(const uint4*)&Kt[d * PST + k0];
    float qv[8], kv[8];
    up2(qw.x, qv[0], qv[1]); up2(qw.y, qv[2], qv[3]);
    up2(qw.z, qv[4], qv[5]); up2(qw.w, qv[6], qv[7]);
    up2(kw.x, kv[0], kv[1]); up2(kw.y, kv[2], kv[3]);
    up2(kw.z, kv[4], kv[5]); up2(kw.w, kv[6], kv[7]);
#pragma unroll
    for (int i = 0; i < 8; ++i)
#pragma unroll
      for (int j = 0; j < 8; ++j) s[i][j] += qv[i] * kv[j];
  }

  // mask penalty depends only on query row; reproduces reference fp32 swamping
  float pen[8];
#pragma unroll
  for (int i = 0; i < 8; ++i)
    pen[i] = (1.0f - (float)mask[(tok0 + q0 + i) * DIM + col0]) * -1e10f;

  float mx[8], sm[8], inv[8];
#pragma unroll
  for (int i = 0; i < 8; ++i) {
    float m0 = -3.4e38f;
#pragma unroll
    for (int j = 0; j < 8; ++j) {
      s[i][j] = s[i][j] * 0.125f + pen[i];
      m0 = fmaxf(m0, s[i][j]);
    }
    mx[i] = m0;
  }
#pragma unroll
  for (int x = 1; x < 16; x <<= 1)
#pragma unroll
    for (int i = 0; i < 8; ++i) mx[i] = fmaxf(mx[i], __shfl_xor(mx[i], x));
#pragma unroll
  for (int i = 0; i < 8; ++i) {
    float a = 0.f;
#pragma unroll
    for (int j = 0; j < 8; ++j) {
      s[i][j] = __expf(s[i][j] - mx[i]);
      a += s[i][j];
    }
    sm[i] = a;
  }
#pragma unroll
  for (int x = 1; x < 16; x <<= 1)
#pragma unroll
    for (int i = 0; i < 8; ++i) sm[i] += __shfl_xor(sm[i], x);
#pragma unroll
  for (int i = 0; i < 8; ++i) inv[i] = 1.0f / sm[i];

  __syncthreads();  // done reading Qt/Kt; safe to overwrite with Pt
#pragma unroll
  for (int j = 0; j < 8; ++j)
#pragma unroll
    for (int i = 0; i < 8; i += 2) {
      uint32_t pw = pk2(s[i][j] * inv[i], s[i + 1][j] * inv[i + 1]);
      *(uint32_t*)&Pt[(k0 + j) * PST + q0 + i] = pw;  // elem idx even -> 4B aligned
    }
  __syncthreads();

  int dt = t & 15;
  int q0b = (t >> 4) * 8;
  int dv0 = dt * 4;
  float o0[8], o1[8], o2[8], o3[8];
#pragma unroll
  for (int i = 0; i < 8; ++i) { o0[i] = 0.f; o1[i] = 0.f; o2[i] = 0.f; o3[i] = 0.f; }

#pragma unroll 4
  for (int k = 0; k < 128; ++k) {
    uint4 pw = *(const uint4*)&Pt[k * PST + q0b];
    float pv[8];
    up2(pw.x, pv[0], pv[1]); up2(pw.y, pv[2], pv[3]);
    up2(pw.z, pv[4], pv[5]); up2(pw.w, pv[6], pv[7]);
    float4 vv = *(const float4*)&Vs[k * 68 + dv0];
#pragma unroll
    for (int i = 0; i < 8; ++i) {
      o0[i] += pv[i] * vv.x;
      o1[i] += pv[i] * vv.y;
      o2[i] += pv[i] * vv.z;
      o3[i] += pv[i] * vv.w;
    }
  }
#pragma unroll
  for (int i = 0; i < 8; ++i) {
    size_t idx = (tok0 + q0b + i) * DIM + col0 + dv0;
    float4 inp = *(const float4*)(inputs + idx);
    float4 r;
    r.x = o0[i] + inp.x; r.y = o1[i] + inp.y; r.z = o2[i] + inp.z; r.w = o3[i] + inp.w;
    *(float4*)(out + idx) = r;
  }
}

// ---------- residual already applied; in-place LayerNorm over DIM ----------
__global__ __launch_bounds__(256) void ln_kernel(float* __restrict__ io,
                                                 const float* __restrict__ gamma,
                                                 const float* __restrict__ beta) {
  int row = blockIdx.x;
  int t = threadIdx.x;
  float4 x = *(const float4*)(io + (size_t)row * DIM + t * 4);
  float s = x.x + x.y + x.z + x.w;
  float q = x.x * x.x + x.y * x.y + x.z * x.z + x.w * x.w;
#pragma unroll
  for (int off = 1; off < 64; off <<= 1) {
    s += __shfl_xor(s, off);
    q += __shfl_xor(q, off);
  }
  __shared__ float red[8];
  int wid = t >> 6, lane = t & 63;
  if (lane == 0) { red[wid] = s; red[wid + 4] = q; }
  __syncthreads();
  s = red[0] + red[1] + red[2] + red[3];
  q = red[4] + red[5] + red[6] + red[7];
  float mu = s * (1.0f / 1024.0f);
  float var = q * (1.0f / 1024.0f) - mu * mu;
  float rs = 1.0f / sqrtf(var + 1e-3f);
  float4 g = *(const float4*)(gamma + t * 4);
  float4 be = *(const float4*)(beta + t * 4);
  float4 r;
  r.x = g.x * (x.x - mu) * rs + be.x;
  r.y = g.y * (x.y - mu) * rs + be.y;
  r.z = g.z * (x.z - mu) * rs + be.z;
  r.w = g.w * (x.w - mu) * rs + be.w;
  *(float4*)(io + (size_t)row * DIM + t * 4) = r;
}

extern "C" void kernel_launch(void* const* d_in, const int* in_sizes, int n_in,
                              void* d_out, int out_size, void* d_ws, size_t ws_size,
                              hipStream_t stream) {
  (void)in_sizes; (void)n_in; (void)out_size; (void)ws_size;
  const float* inputs = (const float*)d_in[0];
  const int* mask = (const int*)d_in[1];
  const float* w1 = (const float*)d_in[2];
  const float* b1 = (const float*)d_in[3];
  const float* w2 = (const float*)d_in[4];
  const float* b2 = (const float*)d_in[5];
  const float* w3 = (const float*)d_in[6];
  const float* b3 = (const float*)d_in[7];
  const float* gamma = (const float*)d_in[8];
  const float* beta = (const float*)d_in[9];
  float* out = (float*)d_out;

  // workspace layout (140 MB total):
  //   Whi @ 0       (6 MB)   Wlo @ 6 MB   (6 MB)
  //   Q   @ 12 MB   (64 MB)  K   @ 76 MB  (64 MB)
  //   V lives in d_out (GEMM writes it; attn reads it before overwriting — safe per-block)
  char* ws = (char*)d_ws;
  unsigned short* Whi = (unsigned short*)(ws);
  unsigned short* Wlo = (unsigned short*)(ws + ((size_t)6 << 20));
  float* Q = (float*)(ws + ((size_t)12 << 20));
  float* K = (float*)(ws + ((size_t)76 << 20));
  float* V = out;

  hipLaunchKernelGGL(wsplit_kernel, dim3(16, 16, 3), dim3(64, 4), 0, stream,
                     w1, w2, w3, Whi, Wlo);
  hipLaunchKernelGGL(qkv_gemm_kernel, dim3(24, 128), dim3(256), 0, stream,
                     inputs, Whi, Wlo, b1, b2, b3, Q, K, V);
  hipLaunchKernelGGL(attn_kernel, dim3(2048), dim3(256), 0, stream,
                     Q, K, V, mask, inputs, out);
  hipLaunchKernelGGL(ln_kernel, dim3(NTOK), dim3(256), 0, stream,
                     out, gamma, beta);
}